// Round 4
// baseline (327.951 us; speedup 1.0000x reference)
//
#include <hip/hip_runtime.h>

// LinearSelfAttention B=32 P=4 N=1024 D=256 — split kernels (proven structure).
// cv = sum_n softmax(q)_n k_n = (y/S)@Wk + b_k,  y = sum_n e_n x_n  (no K).
//   k_prep: pack Wv/Wo bf16 MFMA fragments, wq fp32, zero y/S.
//   k_sum : SINGLE pass over x (2048 x 256): each thread loads its 64 floats
//           once -> fp32 q-dot (shfl over 32 lanes) -> e=exp(q+bq) -> y from
//           the register-held bf16 copies (one atomic/col/block) -> xb = bf16
//           XOR-swizzled row image (pre-swizzled source for k_vo's DMA, G21).
//   k_cv  : cv_g = (y_g/S_g)@Wk + b_k (128 blocks, proven).
//   k_vo  : out = (relu(x@Wv+b_v).*cv)@Wo + b_o. Mtile=32, 4096 blocks x 256
//           threads (4 waves): small blocks -> 4+ blocks/CU in different
//           phases (block-level latency hiding instead of intra-block
//           pipelining). 16KB LDS tile staged via global_load_lds DMA.
// GEMMs: mfma_f32_16x16x32_bf16, B pre-packed in fragment order
//   frag[ct][kk][lane][j] = W[kk*32+(lane>>4)*8+j][ct*16+(lane&15)]
// C/D: col = ct*16+(lane&15), row = rt*16+(lane>>4)*4+reg.
// LDS/xb row swizzle: 16B chunk (row,c) stored at chunk index c^(row&15).
// xb is linear row-major across tiles: global row r starts at xb + r*256.

typedef float  floatx4 __attribute__((ext_vector_type(4)));
typedef __bf16 bf16x8  __attribute__((ext_vector_type(8)));
typedef unsigned short u16;
typedef u16 u16x8 __attribute__((ext_vector_type(8)));

#define NGRP 128

__device__ __forceinline__ float bf2f(u16 u) {
    union { unsigned int i; float f; } c; c.i = ((unsigned int)u) << 16; return c.f;
}
__device__ __forceinline__ u16 f2bf(float f) {
    union { __bf16 h; u16 u; } c; c.h = (__bf16)f; return c.u;
}
__device__ __forceinline__ floatx4 mfma16(bf16x8 a, bf16x8 b, floatx4 c) {
    return __builtin_amdgcn_mfma_f32_16x16x32_bf16(a, b, c, 0, 0, 0);
}

// 16B global->LDS DMA. lds must be wave-uniform; HW adds lane*16.
__device__ __forceinline__ void dma16(const u16* src, u16* lds) {
    __builtin_amdgcn_global_load_lds(
        (const __attribute__((address_space(1))) unsigned int*)src,
        (__attribute__((address_space(3))) unsigned int*)lds, 16, 0, 0);
}

// ---------------------------------------------------------------------------
// k_prep: repack weights + zero accumulators. Grid 256 x 256.
// ---------------------------------------------------------------------------
__global__ __launch_bounds__(256) void k_prep(
    const float* __restrict__ Wqkv, const float* __restrict__ Wo,
    u16* __restrict__ Wvp, u16* __restrict__ Wop,
    float* __restrict__ wqp, float* __restrict__ y, float* __restrict__ Sg)
{
    const int i = blockIdx.x * 256 + threadIdx.x;
    const int j = i & 7, lane = (i >> 3) & 63, kk = (i >> 9) & 7, ct = i >> 12;
    const int k = kk * 32 + (lane >> 4) * 8 + j;
    Wvp[i] = f2bf(Wqkv[k * 513 + (257 + ct * 16 + (lane & 15))]);
    Wop[i] = f2bf(Wo[k * 256 + (ct * 16 + (lane & 15))]);
    if (i < 256) wqp[i] = Wqkv[i * 513];
    if (i < NGRP * 256) y[i] = 0.f;
    if (i < NGRP) Sg[i] = 0.f;
}

// ---------------------------------------------------------------------------
// k_sum: 2048 blocks x 256 threads, 64 rows/block, single pass.
// Thread t: col chunk cc = t&31 (8 cols), row class r0 = t>>5, rows r0+8i.
// ---------------------------------------------------------------------------
__global__ __launch_bounds__(256) void k_sum(
    const float* __restrict__ x, const float* __restrict__ wqp,
    const float* __restrict__ bqkv,
    float* __restrict__ y, float* __restrict__ Sg, u16* __restrict__ xb)
{
    const int tid = threadIdx.x;
    const int m0 = blockIdx.x * 64;
    const int g  = blockIdx.x >> 4;
    const int cc = tid & 31, r0 = tid >> 5;
    const int w = tid >> 6, lane = tid & 63;
    __shared__ float e_s[64];
    __shared__ float ws4[4 * 256];

    const floatx4 wq0 = *(const floatx4*)(wqp + cc * 8);
    const floatx4 wq1 = *(const floatx4*)(wqp + cc * 8 + 4);
    u16* xt = xb + (size_t)blockIdx.x * 16384;

    float qp[8];
    u16x8 o[8];
#pragma unroll
    for (int i = 0; i < 8; ++i) {
        const int row = r0 + 8 * i;
        const float* xp = x + (size_t)(m0 + row) * 256 + cc * 8;
        floatx4 u0 = *(const floatx4*)xp;
        floatx4 u1 = *(const floatx4*)(xp + 4);
        qp[i] = u0[0] * wq0[0] + u0[1] * wq0[1] + u0[2] * wq0[2] + u0[3] * wq0[3]
              + u1[0] * wq1[0] + u1[1] * wq1[1] + u1[2] * wq1[2] + u1[3] * wq1[3];
        u16x8 t;
        t[0] = f2bf(u0[0]); t[1] = f2bf(u0[1]); t[2] = f2bf(u0[2]); t[3] = f2bf(u0[3]);
        t[4] = f2bf(u1[0]); t[5] = f2bf(u1[1]); t[6] = f2bf(u1[2]); t[7] = f2bf(u1[3]);
        o[i] = t;
        *(u16x8*)(xt + row * 256 + ((cc ^ (row & 15)) * 8)) = t;
    }

    // q reduce over the 32 lanes sharing a row class (xor masks stay in-half)
#pragma unroll
    for (int m = 1; m <= 16; m <<= 1) {
#pragma unroll
        for (int i = 0; i < 8; ++i) qp[i] += __shfl_xor(qp[i], m, 64);
    }
    if ((tid & 31) == 0) {
        const float bq0 = bqkv[0];
#pragma unroll
        for (int i = 0; i < 8; ++i) e_s[r0 + 8 * i] = __expf(qp[i] + bq0);
    }
    __syncthreads();

    // y partials straight from register-held bf16 copies
    float yacc[8];
#pragma unroll
    for (int j = 0; j < 8; ++j) yacc[j] = 0.f;
#pragma unroll
    for (int i = 0; i < 8; ++i) {
        const float e = e_s[r0 + 8 * i];
#pragma unroll
        for (int j = 0; j < 8; ++j) yacc[j] += e * bf2f(o[i][j]);
    }
    // fold the two row classes of a wave (lane <-> lane+32 share cc)
#pragma unroll
    for (int j = 0; j < 8; ++j) yacc[j] += __shfl_xor(yacc[j], 32, 64);
    if (lane < 32) {
#pragma unroll
        for (int j = 0; j < 8; ++j) ws4[w * 256 + lane * 8 + j] = yacc[j];
    }
    __syncthreads();

    if (tid < 64) {
        float e = e_s[tid];
#pragma unroll
        for (int s = 32; s > 0; s >>= 1) e += __shfl_xor(e, s, 64);
        if (tid == 0) atomicAdd(Sg + g, e);
    }
    {
        const float s = ws4[tid] + ws4[256 + tid] + ws4[512 + tid] + ws4[768 + tid];
        atomicAdd(y + g * 256 + tid, s);
    }
}

// ---------------------------------------------------------------------------
// k_cv: cv_g = (y_g/S_g) @ Wk + b_k. 128 blocks x 256 threads (proven).
// ---------------------------------------------------------------------------
__global__ __launch_bounds__(256) void k_cv(
    const float* __restrict__ Wqkv, const float* __restrict__ bqkv,
    const float* __restrict__ y, const float* __restrict__ Sg,
    float* __restrict__ cv)
{
    const int g = blockIdx.x, d = threadIdx.x;
    __shared__ float ys[256];
    ys[d] = y[g * 256 + d] * (1.0f / Sg[g]);
    __syncthreads();
    float acc = bqkv[1 + d];
    const float* wp = Wqkv + 1 + d;
#pragma unroll 4
    for (int t = 0; t < 256; t++) acc += ys[t] * wp[(size_t)t * 513];
    cv[g * 256 + d] = acc;
}

// ---------------------------------------------------------------------------
// k_vo: out = (relu(x@Wv+b_v) .* cv) @ Wo + b_o.
// 4096 blocks x 256 threads (4 waves), Mtile=32 (rows m*32..+31), g = m>>5.
// Wave w owns ct = w + 4*i, i=0..3; acc[4][2] (2 row-tiles of 16).
// ---------------------------------------------------------------------------
__global__ __launch_bounds__(256, 4) void k_vo(
    const u16* __restrict__ xb, const u16* __restrict__ Wvp,
    const u16* __restrict__ Wop, const float* __restrict__ cv,
    const float* __restrict__ bqkv, const float* __restrict__ bo,
    float* __restrict__ out)
{
    const int tid = threadIdx.x;
    const int w = tid >> 6, lane = tid & 63, quad = lane >> 4, n16 = lane & 15;
    const int m = blockIdx.x;
    const int m0 = m * 32;
    const int g  = m >> 5;

    __shared__ u16 As[32 * 256];     // 16 KB swizzled bf16 x-tile, then v-tile
    __shared__ float cvs[256];

    cvs[tid] = cv[g * 256 + tid];

    // stage x tile via DMA (linear; xb rows are pre-swizzled)
    {
        const u16* src = xb + (size_t)m * 8192;
#pragma unroll
        for (int it = 0; it < 4; ++it)
            dma16(src + (size_t)(it * 256 + tid) * 8, &As[(it * 256 + w * 64) * 8]);
    }
    __syncthreads();                 // drains DMA (vmcnt) + cvs visible

    // GEMM-A: v = x @ Wv
    floatx4 acc[4][2];
#pragma unroll
    for (int i = 0; i < 4; i++)
#pragma unroll
        for (int rt = 0; rt < 2; rt++) acc[i][rt] = (floatx4){0.f, 0.f, 0.f, 0.f};
#pragma unroll
    for (int kk = 0; kk < 8; kk++) {
        bf16x8 a[2];
#pragma unroll
        for (int rt = 0; rt < 2; rt++) {
            const int row = rt * 16 + n16;
            a[rt] = __builtin_bit_cast(bf16x8,
                *(const u16x8*)(&As[row * 256 + (((kk * 4 + quad) ^ n16) * 8)]));
        }
#pragma unroll
        for (int i = 0; i < 4; i++) {
            const int ct = w + 4 * i;
            bf16x8 bfr = __builtin_bit_cast(bf16x8,
                *(const u16x8*)(Wvp + (size_t)((ct * 8 + kk) * 64 + lane) * 8));
#pragma unroll
            for (int rt = 0; rt < 2; rt++) acc[i][rt] = mfma16(a[rt], bfr, acc[i][rt]);
        }
    }
    __syncthreads();                 // all waves done reading x tile

    // epilogue 1: v = relu(acc + b_v) * cv -> bf16 back into As
#pragma unroll
    for (int i = 0; i < 4; i++) {
        const int col = (w + 4 * i) * 16 + n16;
        const float bias = bqkv[257 + col];
        const float scale = cvs[col];
        const int cchunk = col >> 3, co = col & 7;
#pragma unroll
        for (int rt = 0; rt < 2; rt++) {
#pragma unroll
            for (int r = 0; r < 4; r++) {
                const int row = rt * 16 + quad * 4 + r;
                As[row * 256 + ((cchunk ^ (row & 15)) * 8) + co] =
                    f2bf(fmaxf(acc[i][rt][r] + bias, 0.f) * scale);
            }
        }
    }
    __syncthreads();

    // GEMM-B: out = v @ Wo
    floatx4 acc2[4][2];
#pragma unroll
    for (int i = 0; i < 4; i++)
#pragma unroll
        for (int rt = 0; rt < 2; rt++) acc2[i][rt] = (floatx4){0.f, 0.f, 0.f, 0.f};
#pragma unroll
    for (int kk = 0; kk < 8; kk++) {
        bf16x8 a[2];
#pragma unroll
        for (int rt = 0; rt < 2; rt++) {
            const int row = rt * 16 + n16;
            a[rt] = __builtin_bit_cast(bf16x8,
                *(const u16x8*)(&As[row * 256 + (((kk * 4 + quad) ^ n16) * 8)]));
        }
#pragma unroll
        for (int i = 0; i < 4; i++) {
            const int ct = w + 4 * i;
            bf16x8 bfr = __builtin_bit_cast(bf16x8,
                *(const u16x8*)(Wop + (size_t)((ct * 8 + kk) * 64 + lane) * 8));
#pragma unroll
            for (int rt = 0; rt < 2; rt++) acc2[i][rt] = mfma16(a[rt], bfr, acc2[i][rt]);
        }
    }

    // epilogue 2: out stores
#pragma unroll
    for (int i = 0; i < 4; i++) {
        const int col = (w + 4 * i) * 16 + n16;
        const float bias = bo[col];
#pragma unroll
        for (int rt = 0; rt < 2; rt++) {
            const int rowb = m0 + rt * 16 + quad * 4;
#pragma unroll
            for (int r = 0; r < 4; r++)
                out[(size_t)(rowb + r) * 256 + col] = acc2[i][rt][r] + bias;
        }
    }
}

// ---------------------------------------------------------------------------
extern "C" void kernel_launch(void* const* d_in, const int* in_sizes, int n_in,
                              void* d_out, int out_size, void* d_ws, size_t ws_size,
                              hipStream_t stream)
{
    const float* x    = (const float*)d_in[0];
    const float* Wqkv = (const float*)d_in[1];
    const float* bqkv = (const float*)d_in[2];
    const float* Wo   = (const float*)d_in[3];
    const float* bo   = (const float*)d_in[4];
    float* out = (float*)d_out;

    char* ws = (char*)d_ws;
    u16*   Wvp = (u16*)(ws);                 //    131,072 B
    u16*   Wop = (u16*)(ws + 131072);        //    131,072 B
    float* wqp = (float*)(ws + 262144);      //      1,024 B
    float* y   = (float*)(ws + 263168);      //    131,072 B
    float* Sg  = (float*)(ws + 394240);      //        512 B
    float* cv  = (float*)(ws + 394752);      //    131,072 B
    u16*   xb  = (u16*)(ws + 525824);        // 67,108,864 B (bf16 swizzled x)
                                             // total 67,634,688 B

    k_prep<<<256,  256, 0, stream>>>(Wqkv, Wo, Wvp, Wop, wqp, y, Sg);
    k_sum <<<2048, 256, 0, stream>>>(x, wqp, bqkv, y, Sg, xb);
    k_cv  <<<NGRP, 256, 0, stream>>>(Wqkv, bqkv, y, Sg, cv);
    k_vo  <<<4096, 256, 0, stream>>>(xb, Wvp, Wop, cv, bqkv, bo, out);
}